// Round 14
// baseline (73.562 us; speedup 1.0000x reference)
//
#include <hip/hip_runtime.h>
#include <hip/hip_bf16.h>

// Dynamic conv2d: B=16, C_in=64, H=W=128, C_out=64, K=5, ks=3, pad=1.
// R14: many small barrier domains. Block = 128 thr (2 waves) = 32-pix window
// x 64 co, 8-row strip; 4-slot ring [8ch][36pix][8] = 18.4 KB -> 4 blocks/CU,
// each an independent 2-wave barrier domain (stalls overlap across blocks).
// A-half per wave in registers (proven); w-halo staged 1-value-per-thread.

typedef __attribute__((ext_vector_type(8))) __bf16 bf16x8;
typedef __attribute__((ext_vector_type(16))) float f32x16;
typedef __attribute__((ext_vector_type(4))) unsigned int u32x4;

#define NB 16
#define CI 64
#define CO 64
#define HH 128
#define WW 128
#define KBANK 5
#define ASTR 36864            // shorts of aggw per b: 2m * 36ks * 2g * 32co5 * 8j

__device__ __forceinline__ unsigned short f2bfu(float f) {
    __hip_bfloat16 h = __float2bfloat16(f);
    unsigned short s;
    __builtin_memcpy(&s, &h, 2);
    return s;
}

// ---------------- kernel 1: aggregate weights + bias ----------------
// aggw per b: [m(2)][ks(36)][g(2)][co5(32)][j(8)]; k = ks*16+g*8+j,
// tap = k>>6, ci = k&63, co = m*32+co5. Wave A-load = contiguous 1KB.
__global__ void prep_kernel(const float* __restrict__ weights,
                            const float* __restrict__ Wbank,
                            const float* __restrict__ bbank,
                            short* __restrict__ aggw,
                            float* __restrict__ aggb) {
    int idx = blockIdx.x * 256 + threadIdx.x;          // < 16*36864
    int b   = idx / ASTR;
    int rem = idx - b * ASTR;
    int j   = rem & 7;
    int co5 = (rem >> 3) & 31;
    int g   = (rem >> 8) & 1;
    int mk  = rem >> 9;
    int m   = mk / 36;
    int ks  = mk - m * 36;
    int co  = m * 32 + co5;
    int k   = ks * 16 + g * 8 + j;
    int tap = k >> 6;
    int ci  = k & 63;
    float s = 0.f;
#pragma unroll
    for (int kk = 0; kk < KBANK; ++kk)
        s += weights[b * KBANK + kk] * Wbank[((kk * CO + co) * CI + ci) * 9 + tap];
    aggw[idx] = (short)f2bfu(s);
    if (k == 0) {
        float sb = 0.f;
#pragma unroll
        for (int kk = 0; kk < KBANK; ++kk)
            sb += weights[b * KBANK + kk] * bbank[kk * CO + co];
        aggb[b * CO + co] = sb;
    }
}

// ---------------- kernel 2: streaming conv, 2-wave blocks ----------------
#define WAITL0   asm volatile("s_waitcnt lgkmcnt(0)" ::: "memory")
#define SBAR     do { __builtin_amdgcn_s_barrier(); __builtin_amdgcn_sched_barrier(0); } while (0)

__global__ __launch_bounds__(128, 2) void conv_kernel(const float* __restrict__ x,
                                                      const short* __restrict__ aggw,
                                                      const float* __restrict__ aggb,
                                                      float* __restrict__ out) {
    __shared__ short ring[4][8][36][8];                // 18,432 B

    const int t   = threadIdx.x;                       // 0..127
    // XCD-chunked: logical = (bid&7)*128 + bid>>3 ; each XCD owns 2 b's.
    const int logical = (blockIdx.x & 7) * 128 + (blockIdx.x >> 3);   // 0..1023
    const int b     = logical >> 6;
    const int rem   = logical & 63;
    const int strip = rem >> 2;                        // 0..15
    const int pq    = rem & 3;                         // pix quarter
    const int r0    = strip * 8;
    const int P     = pq * 32;

    const int l  = t & 63;
    const int m  = t >> 6;         // wave = co half
    const int lm = l & 31;
    const int g  = l >> 5;

    const int sw  = t & 31;        // staging: local pix 0..31 (w = P+sw)
    const int scg = t >> 5;        // staging: 16-ci group 0..3

    // halo: thread t stages ONE value: side = t>>6, ci = t&63
    const int hside = t >> 6;
    const int hci   = t & 63;
    const int hw    = P - 1 + hside * 33;              // w = P-1 or P+32
    const int hpix  = hside * 33;                      // pix 0 or 33
    const bool hvw  = ((unsigned)hw < 128u);

    const float* xb = x + (size_t)b * CI * HH * WW;
    const short* Ab = aggw + (size_t)b * ASTR + (size_t)m * 36 * 512;

    // A-half into registers (36 x bf16x8 = 144 VGPR), coalesced 1KB/wave
    bf16x8 A[36];
#pragma unroll
    for (int ks = 0; ks < 36; ++ks)
        A[ks] = *(const bf16x8*)(Ab + ks * 512 + l * 8);

    float bias[16];
#pragma unroll
    for (int rg = 0; rg < 16; ++rg)
        bias[rg] = aggb[b * CO + m * 32 + (rg & 3) + 8 * (rg >> 2) + 4 * g];

    float pv[16];
    // ---- prologue: rows r0-1, r0, r0+1 -> slots 0,1,2 ----
#pragma unroll
    for (int pr = 0; pr < 3; ++pr) {
        const int r = r0 - 1 + pr;
        const bool rv = ((unsigned)r < 128u);
        float hval = 0.f;
        if (rv) {
#pragma unroll
            for (int i = 0; i < 16; ++i)
                pv[i] = xb[((size_t)(scg * 16 + i) * HH + r) * WW + P + sw];
            if (hvw) hval = xb[((size_t)hci * HH + r) * WW + hw];
        } else {
#pragma unroll
            for (int i = 0; i < 16; ++i) pv[i] = 0.f;
        }
#pragma unroll
        for (int h = 0; h < 2; ++h) {
            unsigned u0 = (unsigned)f2bfu(pv[h * 8 + 0]) | ((unsigned)f2bfu(pv[h * 8 + 1]) << 16);
            unsigned u1 = (unsigned)f2bfu(pv[h * 8 + 2]) | ((unsigned)f2bfu(pv[h * 8 + 3]) << 16);
            unsigned u2 = (unsigned)f2bfu(pv[h * 8 + 4]) | ((unsigned)f2bfu(pv[h * 8 + 5]) << 16);
            unsigned u3 = (unsigned)f2bfu(pv[h * 8 + 6]) | ((unsigned)f2bfu(pv[h * 8 + 7]) << 16);
            *(u32x4*)&ring[pr][scg * 2 + h][sw + 1][0] = u32x4{u0, u1, u2, u3};
        }
        ring[pr][hci >> 3][hpix][hci & 7] = (short)f2bfu(hval);
    }
    WAITL0; SBAR;

    // ---- 8 row-steps ----
#pragma unroll
    for (int s = 0; s < 8; ++s) {
        const int r = r0 + s;

        // issue next-row loads at step start (consumed after MFMA)
        float hval = 0.f;
        const int rn = r + 2;
        const bool stg = (s < 7);
        if (stg) {
            if (rn < 128) {
#pragma unroll
                for (int i = 0; i < 16; ++i)
                    pv[i] = xb[((size_t)(scg * 16 + i) * HH + rn) * WW + P + sw];
                if (hvw) hval = xb[((size_t)hci * HH + rn) * WW + hw];
            } else {
#pragma unroll
                for (int i = 0; i < 16; ++i) pv[i] = 0.f;
            }
        }

        // MFMA: output row r from slots s, s+1, s+2 (mod 4)
        f32x16 acc = (f32x16)0.0f;
        __builtin_amdgcn_s_setprio(1);
#pragma unroll
        for (int ks = 0; ks < 36; ++ks) {
            const int tap = ks >> 2, q = ks & 3;
            const int dy = tap / 3, dx = tap - dy * 3;
            const short* sb = &ring[(s + dy) & 3][0][0][0];
            bf16x8 bv = *(const bf16x8*)&sb[((q * 2 + g) * 36 + lm + dx) * 8];
            acc = __builtin_amdgcn_mfma_f32_32x32x16_bf16(A[ks], bv, acc, 0, 0, 0);
        }
        __builtin_amdgcn_s_setprio(0);

        // output stores (fire-and-forget)
        const int wc = P + lm;
#pragma unroll
        for (int rg = 0; rg < 16; ++rg) {
            int co = m * 32 + (rg & 3) + 8 * (rg >> 2) + 4 * g;
            out[(((size_t)b * CO + co) * HH + r) * WW + wc] = acc[rg] + bias[rg];
        }

        // stage row r+2 into slot (s+3)&3
        if (stg) {
#pragma unroll
            for (int h = 0; h < 2; ++h) {
                unsigned u0 = (unsigned)f2bfu(pv[h * 8 + 0]) | ((unsigned)f2bfu(pv[h * 8 + 1]) << 16);
                unsigned u1 = (unsigned)f2bfu(pv[h * 8 + 2]) | ((unsigned)f2bfu(pv[h * 8 + 3]) << 16);
                unsigned u2 = (unsigned)f2bfu(pv[h * 8 + 4]) | ((unsigned)f2bfu(pv[h * 8 + 5]) << 16);
                unsigned u3 = (unsigned)f2bfu(pv[h * 8 + 6]) | ((unsigned)f2bfu(pv[h * 8 + 7]) << 16);
                *(u32x4*)&ring[(s + 3) & 3][scg * 2 + h][sw + 1][0] = u32x4{u0, u1, u2, u3};
            }
            ring[(s + 3) & 3][hci >> 3][hpix][hci & 7] = (short)f2bfu(hval);
        }

        WAITL0; SBAR;
    }
}

extern "C" void kernel_launch(void* const* d_in, const int* in_sizes, int n_in,
                              void* d_out, int out_size, void* d_ws, size_t ws_size,
                              hipStream_t stream) {
    const float* x       = (const float*)d_in[0];
    const float* weights = (const float*)d_in[1];
    const float* Wbank   = (const float*)d_in[2];
    const float* bbank   = (const float*)d_in[3];
    float* out = (float*)d_out;

    short* aggw = (short*)d_ws;                          // 1,179,648 B
    float* aggb = (float*)((char*)d_ws + 1179648);       //     4,096 B

    prep_kernel<<<dim3((NB * ASTR) / 256), dim3(256), 0, stream>>>(weights, Wbank, bbank, aggw, aggb);
    conv_kernel<<<dim3(1024), dim3(128), 0, stream>>>(x, aggw, aggb, out);
}

// Round 15
// 49.716 us; speedup vs baseline: 1.4796x; 1.4796x over previous
//
#include <hip/hip_runtime.h>
#include <hip/hip_bf16.h>

// Dynamic conv2d: B=16, C_in=64, H=W=128, C_out=64, K=5, ks=3, pad=1.
// R15 = R12 shell + producer/consumer wave specialization:
//   waves 0-3 (consumers): A in regs, dual-acc MFMA over 64 pix each, stores.
//   waves 4-7 (producers): drain own gll -> LDS convert fp32->bf16 -> issue
//   next row's global_load_lds. Convert overlaps consumer MFMA on separate
//   waves; consumers never wait vmcnt. Same ring schedule as R12.

typedef __attribute__((ext_vector_type(8))) __bf16 bf16x8;
typedef __attribute__((ext_vector_type(16))) float f32x16;
typedef __attribute__((ext_vector_type(4))) unsigned int u32x4;

#define NB 16
#define CI 64
#define CO 64
#define HH 128
#define WW 128
#define KBANK 5
#define ASTR 36864            // shorts of aggw per b: 2m * 36ks * 2g * 32co5 * 8j

__device__ __forceinline__ unsigned short f2bfu(float f) {
    __hip_bfloat16 h = __float2bfloat16(f);
    unsigned short s;
    __builtin_memcpy(&s, &h, 2);
    return s;
}

// ---------------- kernel 1: aggregate weights + bias ----------------
// aggw per b: [m(2)][ks(36)][g(2)][co5(32)][j(8)]; k = ks*16+g*8+j,
// tap = k>>6, ci = k&63, co = m*32+co5. Wave A-load = contiguous 1KB.
__global__ void prep_kernel(const float* __restrict__ weights,
                            const float* __restrict__ Wbank,
                            const float* __restrict__ bbank,
                            short* __restrict__ aggw,
                            float* __restrict__ aggb) {
    int idx = blockIdx.x * 256 + threadIdx.x;          // < 16*36864
    int b   = idx / ASTR;
    int rem = idx - b * ASTR;
    int j   = rem & 7;
    int co5 = (rem >> 3) & 31;
    int g   = (rem >> 8) & 1;
    int mk  = rem >> 9;
    int m   = mk / 36;
    int ks  = mk - m * 36;
    int co  = m * 32 + co5;
    int k   = ks * 16 + g * 8 + j;
    int tap = k >> 6;
    int ci  = k & 63;
    float s = 0.f;
#pragma unroll
    for (int kk = 0; kk < KBANK; ++kk)
        s += weights[b * KBANK + kk] * Wbank[((kk * CO + co) * CI + ci) * 9 + tap];
    aggw[idx] = (short)f2bfu(s);
    if (k == 0) {
        float sb = 0.f;
#pragma unroll
        for (int kk = 0; kk < KBANK; ++kk)
            sb += weights[b * KBANK + kk] * bbank[kk * CO + co];
        aggb[b * CO + co] = sb;
    }
}

// ---------------- kernel 2: specialized streaming conv ----------------
#define WAITV(N) asm volatile("s_waitcnt vmcnt(" #N ")" ::: "memory")
#define WAITL0   asm volatile("s_waitcnt lgkmcnt(0)" ::: "memory")
#define SBAR     do { __builtin_amdgcn_s_barrier(); __builtin_amdgcn_sched_barrier(0); } while (0)

__global__ __launch_bounds__(512, 2) void conv_kernel(const float* __restrict__ x,
                                                      const short* __restrict__ aggw,
                                                      const float* __restrict__ aggb,
                                                      float* __restrict__ out) {
    __shared__ short bring[4][8][130][8];              // bf16 ring, 66,560 B
    __shared__ float fring[2][64][128];                // fp32 ring, 65,536 B

    const int t   = threadIdx.x;
    const int lin = blockIdx.x;                        // 256 blocks
    const int b   = (lin & 7) * 2 + ((lin >> 3) & 1);  // same-b blocks share an XCD
    const int r0  = (lin >> 4) * 8;                    // 8-row strip

    const int l  = t & 63;
    const int wv = t >> 6;                             // 0..7
    const bool is_prod = (wv >= 4);
    const int pt = t & 255;                            // producer thread id (wv>=4)

    const int m  = (wv >> 1) & 1;                      // consumer: co half
    const int nh = wv & 1;                             // consumer: pix half
    const int lm = l & 31;
    const int g  = l >> 5;

    const float* xb = x + (size_t)b * CI * HH * WW;

    // consumer A-half into registers (36 x bf16x8), coalesced 1KB/wave
    bf16x8 A[36];
    float bias[16];
    if (!is_prod) {
        const short* Ab = aggw + (size_t)b * ASTR + (size_t)m * 36 * 512;
#pragma unroll
        for (int ks = 0; ks < 36; ++ks)
            A[ks] = *(const bf16x8*)(Ab + ks * 512 + l * 8);
#pragma unroll
        for (int rg = 0; rg < 16; ++rg)
            bias[rg] = aggb[b * CO + m * 32 + (rg & 3) + 8 * (rg >> 2) + 4 * g];
    }

    // zero pix-halo (pix 0 and 129) of all 4 bf16 slots
    if (t < 64) {
        int slot = t >> 4, ch = (t >> 1) & 7, px = (t & 1) * 129;
        *(u32x4*)&bring[slot][ch][px][0] = u32x4{0u, 0u, 0u, 0u};
    }

    // all-wave stage (prologue only): 4 chunks/thread
    auto stageAll = [&](int r, int fs) {
        float* fbase = &fring[fs][0][0];
#pragma unroll
        for (int i = 0; i < 4; ++i) {
            int c  = i * 512 + t;
            int ci = c >> 5;
            int w  = (c & 31) * 4;
            const float* src = xb + ((size_t)ci * HH + r) * WW + w;
            float* dst = fbase + (size_t)c * 4;        // lane0 ptr = wave base
            __builtin_amdgcn_global_load_lds(
                (const __attribute__((address_space(1))) void*)src,
                (__attribute__((address_space(3))) void*)dst, 16, 0, 0);
        }
    };
    // producer-only stage: 8 chunks/thread over 256 threads
    auto stageProd = [&](int r, int fs) {
        float* fbase = &fring[fs][0][0];
#pragma unroll
        for (int i = 0; i < 8; ++i) {
            int c  = i * 256 + pt;
            int ci = c >> 5;
            int w  = (c & 31) * 4;
            const float* src = xb + ((size_t)ci * HH + r) * WW + w;
            float* dst = fbase + (size_t)c * 4;
            __builtin_amdgcn_global_load_lds(
                (const __attribute__((address_space(1))) void*)src,
                (__attribute__((address_space(3))) void*)dst, 16, 0, 0);
        }
    };
    // all-wave convert (prologue): 2 chunks/thread
    auto convAll = [&](const float* fbase, int bs, bool zero) {
#pragma unroll
        for (int k2 = 0; k2 < 2; ++k2) {
            int c   = k2 * 512 + t;
            int ch  = c >> 7;
            int pix = (c & 127) + 1;
            unsigned u0 = 0, u1 = 0, u2 = 0, u3 = 0;
            if (!zero) {
                const float* p = fbase + ch * 1024 + (pix - 1);
                u0 = (unsigned)f2bfu(p[0])   | ((unsigned)f2bfu(p[128]) << 16);
                u1 = (unsigned)f2bfu(p[256]) | ((unsigned)f2bfu(p[384]) << 16);
                u2 = (unsigned)f2bfu(p[512]) | ((unsigned)f2bfu(p[640]) << 16);
                u3 = (unsigned)f2bfu(p[768]) | ((unsigned)f2bfu(p[896]) << 16);
            }
            *(u32x4*)&bring[bs][ch][pix][0] = u32x4{u0, u1, u2, u3};
        }
    };
    // producer-only convert (loop): 4 chunks/thread over 256 threads
    auto convProd = [&](const float* fbase, int bs, bool zero) {
#pragma unroll
        for (int k2 = 0; k2 < 4; ++k2) {
            int c   = k2 * 256 + pt;
            int ch  = c >> 7;
            int pix = (c & 127) + 1;
            unsigned u0 = 0, u1 = 0, u2 = 0, u3 = 0;
            if (!zero) {
                const float* p = fbase + ch * 1024 + (pix - 1);
                u0 = (unsigned)f2bfu(p[0])   | ((unsigned)f2bfu(p[128]) << 16);
                u1 = (unsigned)f2bfu(p[256]) | ((unsigned)f2bfu(p[384]) << 16);
                u2 = (unsigned)f2bfu(p[512]) | ((unsigned)f2bfu(p[640]) << 16);
                u3 = (unsigned)f2bfu(p[768]) | ((unsigned)f2bfu(p[896]) << 16);
            }
            *(u32x4*)&bring[bs][ch][pix][0] = u32x4{u0, u1, u2, u3};
        }
    };

    // ---- prologue (identical schedule to R12, last stage producer-only) ----
    if (r0 > 0) stageAll(r0 - 1, 1);
    stageAll(r0, 0);
    WAITV(4); SBAR;                                    // r0-1 landed everywhere
    if (r0 > 0) convAll(&fring[1][0][0], 0, false);
    else        convAll(nullptr,         0, true);
    WAITV(0);                                          // r0 landed (own)
    WAITL0; SBAR;                                      // publish bring0
    convAll(&fring[0][0][0], 1, false);                // r0 -> bring1
    stageAll(r0 + 1, 1);
    WAITL0; SBAR;                                      // publish bring1
    WAITV(0); SBAR;                                    // r0+1 landed everywhere
    convAll(&fring[1][0][0], 2, false);                // r0+1 -> bring2
    if (is_prod) stageProd(r0 + 2, 0);                 // f0; in flight into loop
    WAITL0; SBAR;                                      // publish bring2

    // ---- 8 row-steps, specialized ----
#pragma unroll
    for (int s = 0; s < 8; ++s) {
        const int r = r0 + s;

        if (is_prod && s <= 6) { WAITV(0); }           // own gll (row r+2) landed
        SBAR;                                          // joins: fring[s&1] valid all

        if (is_prod) {
            if (s <= 6) {
                if (r + 2 <= 127) convProd(&fring[s & 1][0][0], (s + 3) & 3, false);
                else              convProd(nullptr,             (s + 3) & 3, true);
            }
            if (s <= 5 && r + 3 <= 127) stageProd(r + 3, (s + 1) & 1);
        } else {
            f32x16 accA = (f32x16)0.0f;
            f32x16 accB = (f32x16)0.0f;
#pragma unroll
            for (int ks = 0; ks < 36; ++ks) {
                const int tap = ks >> 2, q = ks & 3;
                const int dy = tap / 3, dx = tap - dy * 3;
                const short* sb = &bring[(s + dy) & 3][0][0][0];
                const int pixA = nh * 64 + lm + dx;
                bf16x8 bvA = *(const bf16x8*)&sb[((q * 2 + g) * 130 + pixA) * 8];
                bf16x8 bvB = *(const bf16x8*)&sb[((q * 2 + g) * 130 + pixA + 32) * 8];
                accA = __builtin_amdgcn_mfma_f32_32x32x16_bf16(A[ks], bvA, accA, 0, 0, 0);
                accB = __builtin_amdgcn_mfma_f32_32x32x16_bf16(A[ks], bvB, accB, 0, 0, 0);
            }
            const int wcA = nh * 64 + lm;
#pragma unroll
            for (int rg = 0; rg < 16; ++rg) {
                int co = m * 32 + (rg & 3) + 8 * (rg >> 2) + 4 * g;
                out[(((size_t)b * CO + co) * HH + r) * WW + wcA] = accA[rg] + bias[rg];
            }
#pragma unroll
            for (int rg = 0; rg < 16; ++rg) {
                int co = m * 32 + (rg & 3) + 8 * (rg >> 2) + 4 * g;
                out[(((size_t)b * CO + co) * HH + r) * WW + wcA + 32] = accB[rg] + bias[rg];
            }
        }

        WAITL0;                                        // own LDS ops drained
        SBAR;                                          // publish bring[s+3]
    }
}

extern "C" void kernel_launch(void* const* d_in, const int* in_sizes, int n_in,
                              void* d_out, int out_size, void* d_ws, size_t ws_size,
                              hipStream_t stream) {
    const float* x       = (const float*)d_in[0];
    const float* weights = (const float*)d_in[1];
    const float* Wbank   = (const float*)d_in[2];
    const float* bbank   = (const float*)d_in[3];
    float* out = (float*)d_out;

    short* aggw = (short*)d_ws;                          // 1,179,648 B
    float* aggb = (float*)((char*)d_ws + 1179648);       //     4,096 B

    prep_kernel<<<dim3((NB * ASTR) / 256), dim3(256), 0, stream>>>(weights, Wbank, bbank, aggw, aggb);
    conv_kernel<<<dim3(256), dim3(512), 0, stream>>>(x, aggw, aggb, out);
}